// Round 5
// baseline (770.510 us; speedup 1.0000x reference)
//
#include <hip/hip_runtime.h>
#include <hip/hip_bf16.h>
#include <math.h>

#define TOK 8192
#define HD 768
#define ID 2048
#define NE 8
#define MSIZE (2048*768)
#define BM 128
#define BK 64
#define R_SHARED 8192
#define R_MAX 25600   // 8192 shared + 16384 routed + 8*128 max padding, = 200*128

typedef int v4i __attribute__((ext_vector_type(4)));
typedef int v16i __attribute__((ext_vector_type(16)));
typedef __attribute__((address_space(1))) void gas_void;
typedef __attribute__((address_space(3))) void las_void;

__device__ __forceinline__ void g2lds16(const void* g, void* l) {
  __builtin_amdgcn_global_load_lds((gas_void*)g, (las_void*)l, 16, 0, 0);
}

__device__ __forceinline__ float clipf(float v, float lo, float hi) {
  return fminf(fmaxf(v, lo), hi);
}

__device__ __forceinline__ float wred_sum(float v) {
#pragma unroll
  for (int o = 32; o > 0; o >>= 1) v += __shfl_down(v, o, 64);
  return v;
}
__device__ __forceinline__ float wred_max(float v) {
#pragma unroll
  for (int o = 32; o > 0; o >>= 1) v = fmaxf(v, __shfl_down(v, o, 64));
  return v;
}

__device__ __forceinline__ const float* matsel(int mat, const float* Wg, const float* Wu,
                                               const float* Wd, const float* sWg,
                                               const float* sWu, const float* sWd) {
  if (mat < 8)  return Wg + (size_t)mat * MSIZE;
  if (mat < 16) return Wu + (size_t)(mat - 8) * MSIZE;
  if (mat < 24) return Wd + (size_t)(mat - 16) * MSIZE;
  if (mat == 24) return sWg;
  if (mat == 25) return sWu;
  return sWd;
}

// ---------------- weight quantization ----------------
__global__ __launch_bounds__(256)
void k_wstats(const float* __restrict__ Wg, const float* __restrict__ Wu,
              const float* __restrict__ Wd, const float* __restrict__ sWg,
              const float* __restrict__ sWu, const float* __restrict__ sWd,
              double* __restrict__ stats) {
  int mat = blockIdx.y;
  const float* p = matsel(mat, Wg, Wu, Wd, sWg, sWu, sWd);
  int tid = threadIdx.x;
  double s = 0.0, sa = 0.0;
  for (size_t i = (size_t)blockIdx.x * 256 + tid; i < (size_t)MSIZE;
       i += (size_t)gridDim.x * 256) {
    double v = (double)p[i];
    s += v; sa += fabs(v);
  }
  __shared__ double rs[256], ra[256];
  rs[tid] = s; ra[tid] = sa; __syncthreads();
  for (int st = 128; st > 0; st >>= 1) {
    if (tid < st) { rs[tid] += rs[tid + st]; ra[tid] += ra[tid + st]; }
    __syncthreads();
  }
  if (tid == 0) {
    atomicAdd(&stats[mat * 2 + 0], rs[0]);
    atomicAdd(&stats[mat * 2 + 1], ra[0]);
  }
}

__global__ void k_wfinal(const double* __restrict__ stats, double* __restrict__ wmean,
                         float* __restrict__ wscale) {
  int m = threadIdx.x;
  if (m < 27) {
    wmean[m] = stats[m * 2] / (double)MSIZE;
    double sc = stats[m * 2 + 1] / (double)MSIZE;
    wscale[m] = (float)fmax(sc, 1e-8);
  }
}

__global__ __launch_bounds__(256)
void k_wquant(const float* __restrict__ Wg, const float* __restrict__ Wu,
              const float* __restrict__ Wd, const float* __restrict__ sWg,
              const float* __restrict__ sWu, const float* __restrict__ sWd,
              const double* __restrict__ wmean, signed char* __restrict__ tw) {
  int mat = blockIdx.y;
  const float* p = matsel(mat, Wg, Wu, Wd, sWg, sWu, sWd);
  const float4* p4 = (const float4*)p;
  int* t4 = (int*)(tw + (size_t)mat * MSIZE);
  double mu = wmean[mat];
  for (int i = blockIdx.x * 256 + threadIdx.x; i < MSIZE / 4; i += gridDim.x * 256) {
    float4 v = p4[i];
    int b0 = ((double)v.x > mu) ? 1 : (((double)v.x < mu) ? -1 : 0);
    int b1 = ((double)v.y > mu) ? 1 : (((double)v.y < mu) ? -1 : 0);
    int b2 = ((double)v.z > mu) ? 1 : (((double)v.z < mu) ? -1 : 0);
    int b3 = ((double)v.w > mu) ? 1 : (((double)v.w < mu) ? -1 : 0);
    t4[i] = (b0 & 255) | ((b1 & 255) << 8) | ((b2 & 255) << 16) | ((b3 & 255) << 24);
  }
}

// ---------------- router ----------------
__global__ __launch_bounds__(256)
void k_router(const float* __restrict__ x, const float* __restrict__ rw,
              const float* __restrict__ rb, float* __restrict__ logits,
              int* __restrict__ top_idx, float* __restrict__ top_w) {
  int wv = threadIdx.x >> 6, ln = threadIdx.x & 63;
  int t = blockIdx.x * 4 + wv;
  const float4* xr = (const float4*)(x + (size_t)t * HD);
  const float4* rw4 = (const float4*)rw;
  float acc[NE] = {};
#pragma unroll
  for (int i = 0; i < 3; ++i) {
    float4 xv = xr[ln + i * 64];
#pragma unroll
    for (int e = 0; e < NE; ++e) {
      float4 w4 = rw4[e * 192 + ln + i * 64];
      acc[e] += xv.x * w4.x + xv.y * w4.y + xv.z * w4.z + xv.w * w4.w;
    }
  }
#pragma unroll
  for (int e = 0; e < NE; ++e) acc[e] = wred_sum(acc[e]);
  if (ln == 0) {
    float lg[NE], m = -1e30f;
#pragma unroll
    for (int e = 0; e < NE; ++e) {
      lg[e] = acc[e] + rb[e];
      logits[(size_t)t * NE + e] = lg[e];
      m = fmaxf(m, lg[e]);
    }
    float p[NE], s = 0.f;
#pragma unroll
    for (int e = 0; e < NE; ++e) { p[e] = expf(lg[e] - m); s += p[e]; }
    float inv = 1.f / s;
#pragma unroll
    for (int e = 0; e < NE; ++e) p[e] *= inv;
    int e1 = 0; float b1 = p[0];
    for (int e = 1; e < NE; ++e) if (p[e] > b1) { b1 = p[e]; e1 = e; }
    int e2 = -1; float b2 = -1.f;
    for (int e = 0; e < NE; ++e) if (e != e1 && p[e] > b2) { b2 = p[e]; e2 = e; }
    float sw = b1 + b2 + 1e-8f;
    top_idx[t * 2 + 0] = e1; top_idx[t * 2 + 1] = e2;
    top_w[t * 2 + 0] = b1 / sw; top_w[t * 2 + 1] = b2 / sw;
  }
}

// single-block LDS histogram of expert assignments
__global__ __launch_bounds__(1024)
void k_hist(const int* __restrict__ top_idx, int* __restrict__ counts) {
  __shared__ int h[NE];
  if (threadIdx.x < NE) h[threadIdx.x] = 0;
  __syncthreads();
  for (int i = threadIdx.x; i < TOK * 2; i += 1024) atomicAdd(&h[top_idx[i]], 1);
  __syncthreads();
  if (threadIdx.x < NE) counts[threadIdx.x] = h[threadIdx.x];
}

__global__ void k_initrows(int* __restrict__ rows_token, float* __restrict__ rows_w,
                           int* __restrict__ rows_expert) {
  int r = blockIdx.x * blockDim.x + threadIdx.x;
  if (r >= R_MAX) return;
  if (r < R_SHARED) { rows_token[r] = r; rows_w[r] = 1.f; rows_expert[r] = NE; }
  else { rows_token[r] = -1; rows_w[r] = 0.f; rows_expert[r] = 0; }
}

__global__ void k_offsets(const int* __restrict__ counts, int* __restrict__ offs,
                          int* __restrict__ fill) {
  if (threadIdx.x == 0) {
    int off = R_SHARED;
    for (int e = 0; e < NE; ++e) {
      offs[e] = off;
      off += ((counts[e] + BM - 1) / BM) * BM;
    }
    offs[NE] = off;
  }
  if (threadIdx.x < NE) fill[threadIdx.x] = 0;
}

// wave-aggregated scatter: one atomic per (wave, expert) instead of per token
__global__ __launch_bounds__(256)
void k_scatter(const int* __restrict__ top_idx, const float* __restrict__ top_w,
               const int* __restrict__ offs, int* __restrict__ fill,
               int* __restrict__ rows_token, float* __restrict__ rows_w,
               int* __restrict__ rows_expert, int* __restrict__ inv_row) {
  int t = blockIdx.x * 256 + threadIdx.x;
  int ln = threadIdx.x & 63;
  unsigned long long lt = (ln == 63) ? 0x7fffffffffffffffull
                                     : ((1ull << ln) - 1);
#pragma unroll
  for (int k = 0; k < 2; ++k) {
    int e = top_idx[t * 2 + k];
    unsigned long long peers = 0;
#pragma unroll
    for (int ee = 0; ee < NE; ++ee) {
      unsigned long long m = __ballot(e == ee);
      if (e == ee) peers = m;
    }
    int lead = __ffsll(peers) - 1;
    int rank = __popcll(peers & lt);
    int base = 0;
    if (ln == lead) base = atomicAdd(&fill[e], __popcll(peers));
    base = __shfl(base, lead, 64);
    int r = offs[e] + base + rank;
    rows_token[r] = t;
    rows_w[r] = top_w[t * 2 + k];
    rows_expert[r] = e;
    inv_row[t * 2 + k] = r;
  }
}

// ---------------- activation quant (x -> xq_g, xq_u) ----------------
__global__ __launch_bounds__(256)
void k_actquant(const float* __restrict__ x, const int* __restrict__ rows_token,
                const int* __restrict__ rows_expert, const float* __restrict__ ng,
                const float* __restrict__ nu, const float* __restrict__ sng,
                const float* __restrict__ snu, signed char* __restrict__ xqg,
                signed char* __restrict__ xqu, float* __restrict__ invg,
                float* __restrict__ invu) {
  int r = blockIdx.x, tid = threadIdx.x;
  int wv = tid >> 6, ln = tid & 63;
  int tok = rows_token[r];
  if (tok < 0) {
    if (tid < 192) {
      ((int*)(xqg + (size_t)r * HD))[tid] = 0;
      ((int*)(xqu + (size_t)r * HD))[tid] = 0;
    }
    if (tid == 0) { invg[r] = 0.f; invu[r] = 0.f; }
    return;
  }
  int e = rows_expert[r];
  const float* wg = (e < NE) ? ng + (size_t)e * HD : sng;
  const float* wu = (e < NE) ? nu + (size_t)e * HD : snu;
  __shared__ float red[3][4];
  float xv[3]; float ss = 0.f;
#pragma unroll
  for (int i = 0; i < 3; ++i) {
    float v = x[(size_t)tok * HD + tid + i * 256];
    v = clipf(v, -100.f, 100.f);
    xv[i] = v; ss += v * v;
  }
  ss = wred_sum(ss);
  if (ln == 0) red[0][wv] = ss;
  __syncthreads();
  float var = fmaxf((red[0][0] + red[0][1] + red[0][2] + red[0][3]) / (float)HD, 1e-5f);
  float rinv = rsqrtf(var + 1e-5f);
  float xng[3], xnu[3]; float ag = 0.f, au = 0.f;
#pragma unroll
  for (int i = 0; i < 3; ++i) {
    float base = clipf(xv[i] * rinv, -10.f, 10.f);
    float tg = clipf(base * wg[tid + i * 256], -50.f, 50.f);
    float tu = clipf(base * wu[tid + i * 256], -50.f, 50.f);
    xng[i] = tg; ag = fmaxf(ag, fabsf(tg));
    xnu[i] = tu; au = fmaxf(au, fabsf(tu));
  }
  ag = wred_max(ag); au = wred_max(au);
  if (ln == 0) { red[1][wv] = ag; red[2][wv] = au; }
  __syncthreads();
  float mg = fmaxf(fmaxf(fmaxf(red[1][0], red[1][1]), fmaxf(red[1][2], red[1][3])), 1e-4f);
  float mu = fmaxf(fmaxf(fmaxf(red[2][0], red[2][1]), fmaxf(red[2][2], red[2][3])), 1e-4f);
  float scg = 127.f / mg, scu = 127.f / mu;
#pragma unroll
  for (int i = 0; i < 3; ++i) {
    xqg[(size_t)r * HD + tid + i * 256] = (signed char)(int)clipf(rintf(xng[i] * scg), -128.f, 127.f);
    xqu[(size_t)r * HD + tid + i * 256] = (signed char)(int)clipf(rintf(xnu[i] * scu), -128.f, 127.f);
  }
  if (tid == 0) { invg[r] = 1.f / scg; invu[r] = 1.f / scu; }
}

// ---------------- shared GEMM core: 128x128 tile, 4 waves (2x2), 64x64/wave,
// mfma_i32_32x32x32_i8. A via LDS in fragment-order (lane-contiguous b128
// reads, conflict-free). B direct global->VGPR (rows are 64B-line granular,
// L1/L2 resident ternary weights) — halves LDS traffic vs staging both.
__device__ __forceinline__ void gemm_core(const signed char* __restrict__ aq,
                                          const signed char* __restrict__ bp,
                                          int row0, int n0, int kdim, int nit,
                                          signed char* As, v16i acc[2][2]) {
  int tid = threadIdx.x, wv = tid >> 6, ln = tid & 63;
  int lr = ln & 31, lh = ln >> 5;
  // staging: wave wv fills regions (mt=wv, kc=j): entry ln = A[mt*32+(ln&31)][kc*32+(ln>>5)*16]
  const signed char* pa[2];
#pragma unroll
  for (int j = 0; j < 2; ++j)
    pa[j] = aq + (size_t)(row0 + wv * 32 + lr) * kdim + j * 32 + lh * 16;
  // B: wave n-strip base; lane lr = row within 32-tile, lh = 16B k-half
  const signed char* pb[2];
#pragma unroll
  for (int j = 0; j < 2; ++j)
    pb[j] = bp + (size_t)(n0 + (wv >> 1) * 64 + j * 32 + lr) * kdim + lh * 16;
  // fragment-order LDS read offsets: region ((wm_tile)*2+kc)*1024 + ln*16
  int offA[2][2];
#pragma unroll
  for (int i = 0; i < 2; ++i)
#pragma unroll
    for (int kc = 0; kc < 2; ++kc)
      offA[i][kc] = ((((wv & 1) * 2 + i) * 2 + kc) << 10) + ln * 16;

  auto stage = [&](int buf) {
#pragma unroll
    for (int j = 0; j < 2; ++j) {
      g2lds16(pa[j], As + buf * 8192 + ((wv * 2 + j) << 10));
      pa[j] += BK;
    }
  };
  auto compute = [&](int buf) {
    v4i b[2][2];
#pragma unroll
    for (int j = 0; j < 2; ++j) {
      b[j][0] = *(const v4i*)(pb[j]);
      b[j][1] = *(const v4i*)(pb[j] + 32);
      pb[j] += BK;
    }
    v4i a[2][2];
#pragma unroll
    for (int i = 0; i < 2; ++i)
#pragma unroll
      for (int kc = 0; kc < 2; ++kc)
        a[i][kc] = *(const v4i*)(As + buf * 8192 + offA[i][kc]);
#pragma unroll
    for (int kc = 0; kc < 2; ++kc)
#pragma unroll
      for (int i = 0; i < 2; ++i)
#pragma unroll
        for (int j = 0; j < 2; ++j)
          acc[i][j] = __builtin_amdgcn_mfma_i32_32x32x32_i8(a[i][kc], b[j][kc], acc[i][j], 0, 0, 0);
  };

  stage(0);
#pragma unroll 1
  for (int it = 0; it < nit; it += 2) {
    __syncthreads();
    if (it + 1 < nit) stage(1);
    compute(0);
    __syncthreads();
    if (it + 2 < nit) stage(0);
    compute(1);
  }
}

// C/D layout (32x32, m74/m101): col = lane&31, row = (reg&3) + 8*(reg>>2) + 4*(lane>>5)

// ---------------- gate GEMM: writes clip(g,±20) bf16 ----------------
__global__ __launch_bounds__(256, 3)
void k_gemm_gate(const signed char* __restrict__ xq, const signed char* __restrict__ tw,
                 const float* __restrict__ wscale, const float* __restrict__ invx,
                 const int* __restrict__ rows_expert, const int* __restrict__ offs,
                 __hip_bfloat16* __restrict__ gbuf) {
  int n0 = blockIdx.x * BM, row0 = blockIdx.y * BM;
  if (row0 >= offs[NE]) return;
  int e = rows_expert[row0];
  int mg = (e < NE) ? e : 24;
  __shared__ __align__(16) signed char As[2 * 8192];
  __shared__ float sx[BM];
  if (threadIdx.x < BM) sx[threadIdx.x] = invx[row0 + threadIdx.x];
  v16i acc[2][2] = {};
  gemm_core(xq, tw + (size_t)mg * MSIZE, row0, n0, HD, HD / BK, As, acc);
  float ws = wscale[mg];
  int wv = threadIdx.x >> 6, ln = threadIdx.x & 63;
  int wm = (wv & 1) * 64, wn = (wv >> 1) * 64;
  int lr = ln & 31, lh = ln >> 5;
#pragma unroll
  for (int i = 0; i < 2; ++i)
#pragma unroll
    for (int j = 0; j < 2; ++j)
#pragma unroll
      for (int r = 0; r < 16; ++r) {
        int row = wm + i * 32 + (r & 3) + 8 * (r >> 2) + 4 * lh;
        int col = n0 + wn + j * 32 + lr;
        float g = (float)acc[i][j][r] * ws * sx[row];
        g = clipf(g, -20.f, 20.f);
        gbuf[(size_t)(row0 + row) * ID + col] = __float2bfloat16(g);
      }
}

// ---------------- up GEMM: h = clip(silu(g)*u) written IN-PLACE over g ------
__global__ __launch_bounds__(256, 3)
void k_gemm_up(const signed char* __restrict__ xq, const signed char* __restrict__ tw,
               const float* __restrict__ wscale, const float* __restrict__ invx,
               const int* __restrict__ rows_expert, const int* __restrict__ offs,
               __hip_bfloat16* __restrict__ gbuf) {
  int n0 = blockIdx.x * BM, row0 = blockIdx.y * BM;
  if (row0 >= offs[NE]) return;
  int e = rows_expert[row0];
  int mu = (e < NE) ? e + 8 : 25;
  __shared__ __align__(16) signed char As[2 * 8192];
  __shared__ float sx[BM];
  if (threadIdx.x < BM) sx[threadIdx.x] = invx[row0 + threadIdx.x];
  v16i acc[2][2] = {};
  gemm_core(xq, tw + (size_t)mu * MSIZE, row0, n0, HD, HD / BK, As, acc);
  float ws = wscale[mu];
  int wv = threadIdx.x >> 6, ln = threadIdx.x & 63;
  int wm = (wv & 1) * 64, wn = (wv >> 1) * 64;
  int lr = ln & 31, lh = ln >> 5;
#pragma unroll
  for (int i = 0; i < 2; ++i)
#pragma unroll
    for (int j = 0; j < 2; ++j)
#pragma unroll
      for (int r = 0; r < 16; ++r) {
        int row = wm + i * 32 + (r & 3) + 8 * (r >> 2) + 4 * lh;
        int col = n0 + wn + j * 32 + lr;
        size_t idx = (size_t)(row0 + row) * ID + col;
        float u = (float)acc[i][j][r] * ws * sx[row];
        float gf = __bfloat162float(gbuf[idx]);
        float sil = gf * __builtin_amdgcn_rcpf(1.f + __expf(-gf));
        float h = clipf(sil * u, -1000.f, 1000.f);
        gbuf[idx] = __float2bfloat16(h);
      }
}

// ---------------- hidden quant (vectorized bf16x2 loads, packed i8 stores) --
__global__ __launch_bounds__(256)
void k_hquant(const __hip_bfloat16* __restrict__ hidden, const int* __restrict__ rows_token,
              const int* __restrict__ rows_expert, const float* __restrict__ nd,
              const float* __restrict__ snd, signed char* __restrict__ hq,
              float* __restrict__ invh) {
  int r = blockIdx.x, tid = threadIdx.x;
  int wv = tid >> 6, ln = tid & 63;
  int tok = rows_token[r];
  if (tok < 0) {
    ((unsigned long long*)(hq + (size_t)r * ID))[tid] = 0ull;
    if (tid == 0) invh[r] = 0.f;
    return;
  }
  int e = rows_expert[r];
  const float2* wn2 = (const float2*)((e < NE) ? nd + (size_t)e * ID : snd);
  const unsigned int* h2 = (const unsigned int*)(hidden + (size_t)r * ID);
  __shared__ float red[2][4];
  float xa[4], xb[4]; float ss = 0.f;
#pragma unroll
  for (int i = 0; i < 4; ++i) {
    unsigned int u = h2[tid + i * 256];
    float a = __uint_as_float(u << 16);
    float b = __uint_as_float(u & 0xffff0000u);
    a = clipf(a, -100.f, 100.f); b = clipf(b, -100.f, 100.f);
    xa[i] = a; xb[i] = b; ss += a * a + b * b;
  }
  ss = wred_sum(ss);
  if (ln == 0) red[0][wv] = ss;
  __syncthreads();
  float var = fmaxf((red[0][0] + red[0][1] + red[0][2] + red[0][3]) / (float)ID, 1e-5f);
  float rinv = rsqrtf(var + 1e-5f);
  float na[4], nb[4]; float amax = 0.f;
#pragma unroll
  for (int i = 0; i < 4; ++i) {
    float2 w = wn2[tid + i * 256];
    float ta = clipf(clipf(xa[i] * rinv, -10.f, 10.f) * w.x, -50.f, 50.f);
    float tb = clipf(clipf(xb[i] * rinv, -10.f, 10.f) * w.y, -50.f, 50.f);
    na[i] = ta; nb[i] = tb;
    amax = fmaxf(amax, fmaxf(fabsf(ta), fabsf(tb)));
  }
  amax = wred_max(amax);
  if (ln == 0) red[1][wv] = amax;
  __syncthreads();
  float mx = fmaxf(fmaxf(fmaxf(red[1][0], red[1][1]), fmaxf(red[1][2], red[1][3])), 1e-4f);
  float sc = 127.f / mx;
  unsigned short* hqs = (unsigned short*)(hq + (size_t)r * ID);
#pragma unroll
  for (int i = 0; i < 4; ++i) {
    int qa = (int)clipf(rintf(na[i] * sc), -128.f, 127.f);
    int qb = (int)clipf(rintf(nb[i] * sc), -128.f, 127.f);
    hqs[tid + i * 256] = (unsigned short)((qa & 255) | ((qb & 255) << 8));
  }
  if (tid == 0) invh[r] = 1.f / sc;
}

// ---------------- down GEMM -> y (f32, plain stores) ----------------
__global__ __launch_bounds__(256, 3)
void k_gemm_down(const signed char* __restrict__ hq, const signed char* __restrict__ tw,
                 const float* __restrict__ wscale, const float* __restrict__ invh,
                 const float* __restrict__ rows_w, const int* __restrict__ rows_expert,
                 const int* __restrict__ offs, float* __restrict__ y) {
  int n0 = blockIdx.x * BM, row0 = blockIdx.y * BM;
  if (row0 >= offs[NE]) return;
  int e = rows_expert[row0];
  int md = (e < NE) ? 16 + e : 26;
  __shared__ __align__(16) signed char As[2 * 8192];
  __shared__ float s_f[BM];
  if (threadIdx.x < BM)
    s_f[threadIdx.x] = invh[row0 + threadIdx.x] * rows_w[row0 + threadIdx.x];
  v16i acc[2][2] = {};
  gemm_core(hq, tw + (size_t)md * MSIZE, row0, n0, ID, ID / BK, As, acc);
  float ws = wscale[md];
  int wv = threadIdx.x >> 6, ln = threadIdx.x & 63;
  int wm = (wv & 1) * 64, wn = (wv >> 1) * 64;
  int lr = ln & 31, lh = ln >> 5;
#pragma unroll
  for (int i = 0; i < 2; ++i)
#pragma unroll
    for (int j = 0; j < 2; ++j)
#pragma unroll
      for (int r = 0; r < 16; ++r) {
        int row = wm + i * 32 + (r & 3) + 8 * (r >> 2) + 4 * lh;
        int col = n0 + wn + j * 32 + lr;
        y[(size_t)(row0 + row) * HD + col] = (float)acc[i][j][r] * ws * s_f[row];
      }
}

// ---------------- final gather: out[t] = clip(y[t] + y[r1] + y[r2]) ---------
__global__ __launch_bounds__(192)
void k_gather(const float* __restrict__ y, const int* __restrict__ inv_row,
              float* __restrict__ out) {
  int t = blockIdx.x, c = threadIdx.x;
  int r1 = inv_row[t * 2 + 0], r2 = inv_row[t * 2 + 1];
  const float4* y4 = (const float4*)y;
  float4 a = y4[(size_t)t * 192 + c];
  float4 b = y4[(size_t)r1 * 192 + c];
  float4 d = y4[(size_t)r2 * 192 + c];
  float4 o;
  o.x = clipf(a.x + b.x + d.x, -10000.f, 10000.f);
  o.y = clipf(a.y + b.y + d.y, -10000.f, 10000.f);
  o.z = clipf(a.z + b.z + d.z, -10000.f, 10000.f);
  o.w = clipf(a.w + b.w + d.w, -10000.f, 10000.f);
  ((float4*)out)[(size_t)t * 192 + c] = o;
}

// ---------------- host launcher ----------------
extern "C" void kernel_launch(void* const* d_in, const int* in_sizes, int n_in,
                              void* d_out, int out_size, void* d_ws, size_t ws_size,
                              hipStream_t stream) {
  (void)in_sizes; (void)n_in; (void)out_size; (void)ws_size;
  const float* x   = (const float*)d_in[0];
  const float* rw  = (const float*)d_in[1];
  const float* rb  = (const float*)d_in[2];
  const float* Wg  = (const float*)d_in[3];
  const float* Wu  = (const float*)d_in[4];
  const float* Wd  = (const float*)d_in[5];
  const float* ng  = (const float*)d_in[6];
  const float* nu  = (const float*)d_in[7];
  const float* nd  = (const float*)d_in[8];
  const float* sWg = (const float*)d_in[9];
  const float* sWu = (const float*)d_in[10];
  const float* sWd = (const float*)d_in[11];
  const float* sng = (const float*)d_in[12];
  const float* snu = (const float*)d_in[13];
  const float* snd = (const float*)d_in[14];
  float* out = (float*)d_out;
  float* logits = out + (size_t)TOK * HD;

  char* ws = (char*)d_ws;
  size_t off = 0;
  auto alloc = [&](size_t b) { size_t o = off; off = (off + b + 255) & ~(size_t)255; return o; };
  signed char* tw   = (signed char*)(ws + alloc((size_t)27 * MSIZE));
  double* stats     = (double*)(ws + alloc(27 * 2 * sizeof(double)));
  double* wmean     = (double*)(ws + alloc(27 * sizeof(double)));
  float* wscale     = (float*)(ws + alloc(27 * sizeof(float)));
  int* counts       = (int*)(ws + alloc(8 * sizeof(int)));
  int* fill         = (int*)(ws + alloc(8 * sizeof(int)));
  int* offs         = (int*)(ws + alloc(16 * sizeof(int)));
  int* top_idx      = (int*)(ws + alloc((size_t)TOK * 2 * sizeof(int)));
  float* top_w      = (float*)(ws + alloc((size_t)TOK * 2 * sizeof(float)));
  int* inv_row      = (int*)(ws + alloc((size_t)TOK * 2 * sizeof(int)));
  int* rows_token   = (int*)(ws + alloc((size_t)R_MAX * sizeof(int)));
  float* rows_w     = (float*)(ws + alloc((size_t)R_MAX * sizeof(float)));
  int* rows_expert  = (int*)(ws + alloc((size_t)R_MAX * sizeof(int)));
  float* invg       = (float*)(ws + alloc((size_t)R_MAX * sizeof(float)));
  float* invu       = (float*)(ws + alloc((size_t)R_MAX * sizeof(float)));
  float* invh       = (float*)(ws + alloc((size_t)R_MAX * sizeof(float)));
  // hq region; xqg/xqu alias its front (safe: xq consumed by gate/up GEMMs before k_hquant writes hq)
  signed char* hq   = (signed char*)(ws + alloc((size_t)R_MAX * ID));
  signed char* xqg  = hq;
  signed char* xqu  = hq + (size_t)R_MAX * HD;
  // hidden region: gate writes g, up rewrites h in-place, hquant reads h;
  // y (78 MB) aliases it afterwards (hidden dead post-hquant).
  char* hid_region  = ws + alloc((size_t)R_MAX * ID * 2);
  __hip_bfloat16* hidden = (__hip_bfloat16*)hid_region;
  float* y          = (float*)hid_region;

  hipMemsetAsync(stats, 0, 27 * 2 * sizeof(double), stream);

  k_wstats<<<dim3(64, 27), 256, 0, stream>>>(Wg, Wu, Wd, sWg, sWu, sWd, stats);
  k_wfinal<<<1, 32, 0, stream>>>(stats, wmean, wscale);
  k_wquant<<<dim3(256, 27), 256, 0, stream>>>(Wg, Wu, Wd, sWg, sWu, sWd, wmean, tw);
  k_router<<<TOK / 4, 256, 0, stream>>>(x, rw, rb, logits, top_idx, top_w);
  k_hist<<<1, 1024, 0, stream>>>(top_idx, counts);
  k_initrows<<<(R_MAX + 255) / 256, 256, 0, stream>>>(rows_token, rows_w, rows_expert);
  k_offsets<<<1, 64, 0, stream>>>(counts, offs, fill);
  k_scatter<<<TOK / 256, 256, 0, stream>>>(top_idx, top_w, offs, fill, rows_token,
                                           rows_w, rows_expert, inv_row);
  k_actquant<<<R_MAX, 256, 0, stream>>>(x, rows_token, rows_expert, ng, nu, sng, snu,
                                        xqg, xqu, invg, invu);
  k_gemm_gate<<<dim3(ID / BM, R_MAX / BM), 256, 0, stream>>>(xqg, tw, wscale, invg,
                                                             rows_expert, offs, hidden);
  k_gemm_up<<<dim3(ID / BM, R_MAX / BM), 256, 0, stream>>>(xqu, tw, wscale, invu,
                                                           rows_expert, offs, hidden);
  k_hquant<<<R_MAX, 256, 0, stream>>>(hidden, rows_token, rows_expert, nd, snd, hq, invh);
  k_gemm_down<<<dim3(HD / BM, R_MAX / BM), 256, 0, stream>>>(hq, tw, wscale, invh,
                                                             rows_w, rows_expert, offs, y);
  k_gather<<<TOK, 192, 0, stream>>>(y, inv_row, out);
}